// Round 5
// baseline (41.441 us; speedup 1.0000x reference)
//
#include <hip/hip_runtime.h>
#include <math.h>

// Problem constants (from reference setup_inputs)
#define N_NODES  2048
#define N_GRAPHS 128
#define NSUB     32
#define SSZ      10
#define NPAIRS   45
#define FEAT     96
#define HIDDEN   128
#define BN_EPS   1e-5f

#define NBLK     512    // 2 blocks/CU -> co-resident everywhere
#define ROWS_PB  4      // 4 waves/block, 1 adjacency row per wave

// ws float offsets
#define WS_C1    0
#define WS_C2    2048
#define WS_FLG   4096                 // int flags[3][512]
#define WS_GEN   (WS_FLG + 1536)      // int gen
#define WS_CG1   (WS_GEN + 8)        // float C1g[128]
#define WS_CG2   (WS_CG1 + 128)      // float C2g[128]
#define WS_CG3   (WS_CG2 + 128)      // float C3g[128]
#define WS_ZBEG  WS_FLG
#define WS_ZEND  (WS_CG3 + 128)

// Cache-bypassing relaxed atomics: complete at the device coherence point ->
// cross-XCD visibility with NO wbl2/inv cache maintenance anywhere.
__device__ __forceinline__ float aload(const float* p) {
    return __hip_atomic_load(const_cast<float*>(p), __ATOMIC_RELAXED, __HIP_MEMORY_SCOPE_AGENT);
}
__device__ __forceinline__ void astore(float* p, float v) {
    __hip_atomic_store(p, v, __ATOMIC_RELAXED, __HIP_MEMORY_SCOPE_AGENT);
}
__device__ __forceinline__ int aiload(int* p) {
    return __hip_atomic_load(p, __ATOMIC_RELAXED, __HIP_MEMORY_SCOPE_AGENT);
}
__device__ __forceinline__ void aistore(int* p, int v) {
    __hip_atomic_store(p, v, __ATOMIC_RELAXED, __HIP_MEMORY_SCOPE_AGENT);
}
__device__ __forceinline__ void afadd(float* p, float v) {
    __hip_atomic_fetch_add(p, v, __ATOMIC_RELAXED, __HIP_MEMORY_SCOPE_AGENT);
}

// Zero-fence, zero-RMW grid barrier (validated round 4: ~1.5-2 us each).
// __syncthreads() drains vmcnt per wave (all data stores/atomics complete at
// the coherence point), then one relaxed flag store per block. Block 0 sweeps
// all 512 flags with 256 threads, bumps gen; others spin on gen.
__device__ __forceinline__ void gbar(int* flags, int* gen, int phase) {
    __syncthreads();
    int* f = flags + (phase << 9);
    if (threadIdx.x == 0) aistore(f + blockIdx.x, 1);
    if (blockIdx.x == 0) {
        while (aiload(f + threadIdx.x) == 0) __builtin_amdgcn_s_sleep(1);
        while (aiload(f + threadIdx.x + 256) == 0) __builtin_amdgcn_s_sleep(1);
        __syncthreads();
        if (threadIdx.x == 0) aistore(gen, phase + 1);
    } else {
        if (threadIdx.x == 0) {
            while (aiload(gen) <= phase) __builtin_amdgcn_s_sleep(1);
        }
        __syncthreads();
    }
}

// arrive-only (no spin) for blocks that don't consume the next phase's data
__device__ __forceinline__ void gbar_arrive(int* flags, int phase) {
    __syncthreads();
    if (threadIdx.x == 0) aistore(flags + (phase << 9) + blockIdx.x, 1);
}

__global__ __launch_bounds__(256)
void rwgnn_persist(const float* __restrict__ adj,
                   const int*   __restrict__ gi,
                   const float* __restrict__ theta,
                   const float* __restrict__ gamma,
                   const float* __restrict__ beta,
                   const float* __restrict__ w1,
                   const float* __restrict__ b1,
                   const float* __restrict__ w2,
                   const float* __restrict__ b2,
                   float* __restrict__ out,
                   float* __restrict__ ws)
{
    __shared__ __align__(16) float c_lds[N_NODES];   // 8 KB staging for c1/c2
    __shared__ float cnt_s[N_GRAPHS];
    __shared__ float Vl[3][NSUB];
    __shared__ float yl[3][N_GRAPHS];
    __shared__ float mv[6];
    __shared__ float xr[FEAT];
    __shared__ float red[4];

    const int tid  = threadIdx.x;
    const int wv   = tid >> 6;
    const int lane = tid & 63;
    const int bid  = blockIdx.x;

    float* c1  = ws + WS_C1;
    float* c2  = ws + WS_C2;
    int* flags = (int*)(ws + WS_FLG);
    int* gen   = (int*)(ws + WS_GEN);
    float* C1g = ws + WS_CG1;
    float* C2g = ws + WS_CG2;
    float* C3g = ws + WS_CG3;

    const int row = bid * ROWS_PB + wv;
    const float* Ar = adj + (size_t)row * N_NODES;
    const int grow = gi[row];                 // graph of my row

    // ---- P1: c1[row] = rowsum(A); also C1g[g] += c1[row] ----
    {
        float s = 0.f;
        #pragma unroll
        for (int c = lane * 4; c < N_NODES; c += 256) {
            float4 a = *reinterpret_cast<const float4*>(Ar + c);
            s += (a.x + a.y) + (a.z + a.w);
        }
        #pragma unroll
        for (int o = 32; o; o >>= 1) s += __shfl_down(s, o);
        if (lane == 0) { astore(&c1[row], s); afadd(&C1g[grow], s); }
    }
    gbar(flags, gen, 0);

    // ---- P2: stage c1 -> LDS once per block; c2[row] = A[row] . c1 ----
    #pragma unroll
    for (int k = 0; k < 8; k++) c_lds[k * 256 + tid] = aload(&c1[k * 256 + tid]);
    __syncthreads();
    {
        float s = 0.f;
        #pragma unroll
        for (int c = lane * 4; c < N_NODES; c += 256) {
            float4 a = *reinterpret_cast<const float4*>(Ar + c);
            float4 x = *reinterpret_cast<const float4*>(&c_lds[c]);
            s += a.x * x.x + a.y * x.y + a.z * x.z + a.w * x.w;
        }
        #pragma unroll
        for (int o = 32; o; o >>= 1) s += __shfl_down(s, o);
        if (lane == 0) { astore(&c2[row], s); afadd(&C2g[grow], s); }
    }
    gbar(flags, gen, 1);

    // ---- P3: stage c2 -> LDS; C3g[g] += A[row] . c2 (c3 never materialized) ----
    #pragma unroll
    for (int k = 0; k < 8; k++) c_lds[k * 256 + tid] = aload(&c2[k * 256 + tid]);
    __syncthreads();
    {
        float s = 0.f;
        #pragma unroll
        for (int c = lane * 4; c < N_NODES; c += 256) {
            float4 a = *reinterpret_cast<const float4*>(Ar + c);
            float4 x = *reinterpret_cast<const float4*>(&c_lds[c]);
            s += a.x * x.x + a.y * x.y + a.z * x.z + a.w * x.w;
        }
        #pragma unroll
        for (int o = 32; o; o >>= 1) s += __shfl_down(s, o);
        if (lane == 0) afadd(&C3g[grow], s);
    }

    // blocks that don't run the tail: arrive and exit
    if (bid >= N_GRAPHS) { gbar_arrive(flags, 2); return; }
    gbar(flags, gen, 2);

    // ---- Tail (blocks 0..127, redundant): stats + BN + MLP for graph g=bid ----
    const int g = bid;

    if (tid < N_GRAPHS) cnt_s[tid] = 0.f;
    __syncthreads();
    for (int n = tid; n < N_NODES; n += 256) atomicAdd(&cnt_s[gi[n]], 1.f);

    // V_i[s] = 1^T A_s^i 1 without materializing A_s
    if (tid < NSUB) {
        const float* th = theta + tid * NPAIRS;
        float u1[SSZ];
        #pragma unroll
        for (int k = 0; k < SSZ; k++) u1[k] = 0.f;
        float sumT = 0.f;
        #pragma unroll
        for (int i = 0; i < SSZ; i++) {
            #pragma unroll
            for (int j = i + 1; j < SSZ; j++) {
                const int p = i * (2 * SSZ - 1 - i) / 2 + (j - i - 1);
                float t = th[p]; t = t > 0.f ? t : 0.f;
                sumT += t; u1[i] += t; u1[j] += t;
            }
        }
        float V2 = 0.f;
        #pragma unroll
        for (int k = 0; k < SSZ; k++) V2 += u1[k] * u1[k];
        float V3 = 0.f;
        #pragma unroll
        for (int i = 0; i < SSZ; i++) {
            #pragma unroll
            for (int j = i + 1; j < SSZ; j++) {
                const int p = i * (2 * SSZ - 1 - i) / 2 + (j - i - 1);
                float t = th[p]; t = t > 0.f ? t : 0.f;
                V3 += t * u1[i] * u1[j];
            }
        }
        Vl[0][tid] = 2.f * sumT;
        Vl[1][tid] = V2;
        Vl[2][tid] = 2.f * V3;
    }
    __syncthreads();

    // y_i[g'] = C_i[g'] / counts[g']  (C sums read once, uncached)
    if (tid < N_GRAPHS) {
        float inv = 1.f / cnt_s[tid];
        yl[0][tid] = aload(&C1g[tid]) * inv;
        yl[1][tid] = aload(&C2g[tid]) * inv;
        yl[2][tid] = aload(&C3g[tid]) * inv;
    }
    __syncthreads();

    // batch mean/var over 128 graphs: wave i handles step i
    if (wv < 3) {
        float a = yl[wv][lane], b = yl[wv][lane + 64];
        float s = a + b;
        #pragma unroll
        for (int o = 32; o; o >>= 1) s += __shfl_xor(s, o);
        float m = s * (1.f / N_GRAPHS);
        float da = a - m, db = b - m;
        float v = da * da + db * db;
        #pragma unroll
        for (int o = 32; o; o >>= 1) v += __shfl_xor(v, o);
        v *= (1.f / N_GRAPHS);
        if (lane == 0) { mv[wv] = m; mv[3 + wv] = v; }
    }
    __syncthreads();

    if (tid < FEAT) {
        int i = tid >> 5;
        float V = Vl[i][tid & 31];
        float scale = gamma[tid] * rsqrtf(V * V * mv[3 + i] + BN_EPS);
        xr[tid] = scale * V * (yl[i][g] - mv[i]) + beta[tid];
    }
    __syncthreads();

    if (tid < HIDDEN) {
        float acc = b1[tid];
        #pragma unroll
        for (int f = 0; f < FEAT; f++)
            acc = fmaf(xr[f], w1[f * HIDDEN + tid], acc);
        float h = fmaxf(acc, 0.f);
        float2 w2v = *reinterpret_cast<const float2*>(w2 + 2 * tid);
        float p0 = h * w2v.x, p1 = h * w2v.y;
        #pragma unroll
        for (int o = 32; o; o >>= 1) { p0 += __shfl_down(p0, o); p1 += __shfl_down(p1, o); }
        int w = tid >> 6, l = tid & 63;
        if (l == 0) { red[2 * w] = p0; red[2 * w + 1] = p1; }
    }
    __syncthreads();
    if (tid == 0) {
        out[2 * g + 0] = red[0] + red[2] + b2[0];
        out[2 * g + 1] = red[1] + red[3] + b2[1];
    }
}

extern "C" void kernel_launch(void* const* d_in, const int* in_sizes, int n_in,
                              void* d_out, int out_size, void* d_ws, size_t ws_size,
                              hipStream_t stream) {
    const float* adj   = (const float*)d_in[0];
    const int*   gi    = (const int*)  d_in[1];
    const float* theta = (const float*)d_in[2];
    const float* gamma = (const float*)d_in[3];
    const float* beta  = (const float*)d_in[4];
    const float* w1    = (const float*)d_in[5];
    const float* b1    = (const float*)d_in[6];
    const float* w2    = (const float*)d_in[7];
    const float* b2    = (const float*)d_in[8];
    float* out = (float*)d_out;
    float* ws  = (float*)d_ws;

    // zero flags + gen + C accumulators each call (graph-legal async memset)
    hipMemsetAsync((char*)d_ws + WS_ZBEG * sizeof(float), 0,
                   (WS_ZEND - WS_ZBEG) * sizeof(float), stream);

    rwgnn_persist<<<NBLK, 256, 0, stream>>>(adj, gi, theta, gamma, beta,
                                            w1, b1, w2, b2, out, ws);
}